// Round 3
// baseline (342.240 us; speedup 1.0000x reference)
//
#include <hip/hip_runtime.h>

// MultiGridAgentEncoder v4:
//  - pre-kernel swizzles W -> bf16 in MFMA-fragment order (d_ws), K remapped to
//    slot-stride-14 layout (9 slots x 14, K=126 -> pad 128)
//  - unified slot-unit ballot gather (u==0 query, u==1..8 agent slots), every
//    (row,slot) written fully -> no zero phase for the X body
//  - column-half-split MFMA (32 cols at a time) keeps VGPR <= 64
//  - operand-swapped MFMA -> lane holds 4 consecutive output cols -> dwordx4 stores
//  - grid 1024 (1 chunk/block) + __launch_bounds__(512,8) -> 4 blocks/CU resident

#define TM 128          // rows per block
#define XS_LD 136       // LDS row stride in halves (126 used + 10 pad)
#define THREADS 512     // 8 waves: wave grid 2 (rows) x 4 (col-groups of 64)
#define NCOL 256

typedef short short8 __attribute__((ext_vector_type(8)));
typedef float f32x4 __attribute__((ext_vector_type(4)));

__device__ __forceinline__ short f2bf(float x) {
    unsigned u = __builtin_bit_cast(unsigned, x);
    unsigned r = (u + 0x7fffu + ((u >> 16) & 1u)) >> 16;
    return (short)r;
}
__device__ __forceinline__ unsigned pk2(float a, float b) {
    return (unsigned)(unsigned short)f2bf(a) | ((unsigned)(unsigned short)f2bf(b) << 16);
}

// ---- pre-kernel: W (117x256 f32) -> Wb bf16 fragment-order, slot-stride-14 K ----
// Wb[((cg*4 + kt)*4 + ct)*64 + lane][j] = bf16( Wx[kt*32 + (lane>>4)*8 + j][cg*64 + ct*16 + (lane&15)] )
// Wx[14u + f][c] = W[(13u + f)*256 + c] for u<9, f<13, else 0.
__global__ __launch_bounds__(256)
void swz_w_kernel(const float* __restrict__ W, short* __restrict__ Wb) {
    const int idx  = blockIdx.x * 256 + threadIdx.x;   // 0..32767
    const int j    = idx & 7;
    const int lane = (idx >> 3) & 63;
    const int ct   = (idx >> 9) & 3;
    const int kt   = (idx >> 11) & 3;
    const int cg   = (idx >> 13) & 3;
    const int kk   = kt * 32 + (lane >> 4) * 8 + j;
    const int u    = kk / 14;
    const int f    = kk - u * 14;
    const int col  = cg * 64 + ct * 16 + (lane & 15);
    float v = 0.f;
    if (u < 9 && f < 13) v = W[(u * 13 + f) * NCOL + col];
    Wb[idx] = f2bf(v);
}

template<bool WS>
__global__ __launch_bounds__(THREADS, 8)
void mga_encoder_kernel(const float* __restrict__ qpos, const float* __restrict__ qdir,
                        const float* __restrict__ qabil, const float* __restrict__ qcarr,
                        const float* __restrict__ qstat,
                        const float* __restrict__ apos, const float* __restrict__ adir,
                        const float* __restrict__ aabil, const float* __restrict__ acarr,
                        const float* __restrict__ astat,
                        const int* __restrict__ cidx,
                        const float* __restrict__ W, const float* __restrict__ bvec,
                        const short* __restrict__ Wb,
                        float* __restrict__ out) {
    __shared__ __align__(16) short Xs[TM * XS_LD];

    const int tid  = threadIdx.x;
    const int wave = tid >> 6;
    const int lane = tid & 63;
    const int ln   = lane & 15;
    const int q    = lane >> 4;
    const int r0w  = (wave & 1) * 64;
    const int cg   = wave >> 1;
    const int c0   = cg * 64;
    const int rowbase = blockIdx.x * TM;

    // zero the K-pad region (halves [126,136) of each row)
    #pragma unroll
    for (int i = tid; i < TM * 5; i += THREADS) {
        const int row = i / 5, w = i - row * 5;
        *(unsigned*)&Xs[row * XS_LD + 126 + w * 2] = 0u;
    }

    const int rr  = tid >> 4;   // row-within-pass (0..31)
    const int u   = tid & 15;   // slot unit: 0 = query, 1..8 = agent slots
    const int grp = tid & 48;   // start lane of 16-lane row group

    // ---- gather: 4 passes of 32 rows; each 16-lane group handles one row ----
    int cs[4];
    #pragma unroll
    for (int p = 0; p < 4; p++)
        cs[p] = cidx[((size_t)(rowbase + p * 32 + rr)) * 16 + u];

    #pragma unroll
    for (int p = 0; p < 4; p++) {
        const int r = p * 32 + rr;
        const size_t b = (size_t)(rowbase + r);
        const int c = cs[p];
        const unsigned long long bg = __ballot(c == 5);  // grey
        const unsigned long long by = __ballot(c == 4);  // yellow
        if (u <= 8) {
            float f0=0.f,f1=0.f,f2=0.f,f3=0.f,f4=0.f,f5=0.f,f6=0.f,
                  f7=0.f,f8=0.f,f9=0.f,f10=0.f,f11=0.f,f12=0.f;
            if (u == 0) {
                const float2 qp = ((const float2*)qpos)[b];
                const float4 qd = ((const float4*)qdir)[b];
                const float2 qa = ((const float2*)qabil)[b];
                const float2 qc = ((const float2*)qcarr)[b];
                f0 = qp.x; f1 = qp.y;
                f2 = qd.x; f3 = qd.y; f4 = qd.z; f5 = qd.w;
                f6 = qa.x; f7 = qa.y;
                f8 = qc.x; f9 = qc.y;
                f10 = qstat[b * 3 + 0]; f11 = qstat[b * 3 + 1]; f12 = qstat[b * 3 + 2];
            } else {
                unsigned mm = (unsigned)(((u <= 4) ? bg : by) >> grp) & 0xFFFFu;
                const int rank = (u - 1) & 3;
                mm = (rank > 0) ? (mm & (mm - 1)) : mm;
                mm = (rank > 1) ? (mm & (mm - 1)) : mm;
                mm = (rank > 2) ? (mm & (mm - 1)) : mm;
                const int j = mm ? (__ffs(mm) - 1) : -1;
                if (j >= 0) {
                    const size_t a = b * 16 + (size_t)j;
                    const float2 pp = ((const float2*)apos)[a];
                    const float4 dd = ((const float4*)adir)[a];
                    const float2 ab = ((const float2*)aabil)[a];
                    const float2 ca = ((const float2*)acarr)[a];
                    f0 = pp.x; f1 = pp.y;
                    f2 = dd.x; f3 = dd.y; f4 = dd.z; f5 = dd.w;
                    f6 = ab.x; f7 = ab.y; f8 = ca.x; f9 = ca.y;
                    f10 = astat[a * 3 + 0]; f11 = astat[a * 3 + 1]; f12 = astat[a * 3 + 2];
                }
            }
            unsigned* xd = (unsigned*)&Xs[r * XS_LD + 14 * u];
            xd[0] = pk2(f0, f1);   xd[1] = pk2(f2, f3);
            xd[2] = pk2(f4, f5);   xd[3] = pk2(f6, f7);
            xd[4] = pk2(f8, f9);   xd[5] = pk2(f10, f11);
            xd[6] = pk2(f12, 0.f);
        }
    }
    __syncthreads();

    // ---- MFMA in two column halves (32 cols each) to keep regs <= 64 ----
    const short8* Wf = (const short8*)Wb;
    #pragma unroll 1
    for (int h = 0; h < 2; h++) {
        short8 bfr[4][2];
        if constexpr (WS) {
            #pragma unroll
            for (int kt = 0; kt < 4; kt++)
                #pragma unroll
                for (int cc = 0; cc < 2; cc++)
                    bfr[kt][cc] = Wf[((cg * 4 + kt) * 4 + 2 * h + cc) * 64 + lane];
        } else {
            #pragma unroll
            for (int kt = 0; kt < 4; kt++)
                #pragma unroll
                for (int cc = 0; cc < 2; cc++) {
                    short8 fr;
                    #pragma unroll
                    for (int j = 0; j < 8; j++) {
                        const int kk = kt * 32 + q * 8 + j;
                        const int uu = kk / 14;
                        const int ff = kk - uu * 14;
                        float v = 0.f;
                        if (uu < 9 && ff < 13)
                            v = W[(uu * 13 + ff) * NCOL + c0 + (2 * h + cc) * 16 + ln];
                        fr[j] = f2bf(v);
                    }
                    bfr[kt][cc] = fr;
                }
        }
        f32x4 bv[2];
        #pragma unroll
        for (int cc = 0; cc < 2; cc++)
            bv[cc] = *(const f32x4*)&bvec[c0 + (2 * h + cc) * 16 + q * 4];

        f32x4 acc[4][2];
        #pragma unroll
        for (int rt = 0; rt < 4; rt++)
            #pragma unroll
            for (int cc = 0; cc < 2; cc++) acc[rt][cc] = (f32x4){0.f, 0.f, 0.f, 0.f};

        #pragma unroll
        for (int kt = 0; kt < 4; kt++) {
            short8 av[4];
            #pragma unroll
            for (int rt = 0; rt < 4; rt++)
                av[rt] = *(const short8*)&Xs[(r0w + rt * 16 + ln) * XS_LD + kt * 32 + q * 8];
            #pragma unroll
            for (int rt = 0; rt < 4; rt++)
                #pragma unroll
                for (int cc = 0; cc < 2; cc++)
                    // swapped operands: lane holds 4 consecutive OUTPUT COLUMNS
                    acc[rt][cc] = __builtin_amdgcn_mfma_f32_16x16x32_bf16(
                        bfr[kt][cc], av[rt], acc[rt][cc], 0, 0, 0);
        }

        #pragma unroll
        for (int rt = 0; rt < 4; rt++) {
            const int row = rowbase + r0w + rt * 16 + ln;
            #pragma unroll
            for (int cc = 0; cc < 2; cc++) {
                const int col = c0 + (2 * h + cc) * 16 + q * 4;
                f32x4 v;
                v[0] = fmaxf(acc[rt][cc][0] + bv[cc][0], 0.f);
                v[1] = fmaxf(acc[rt][cc][1] + bv[cc][1], 0.f);
                v[2] = fmaxf(acc[rt][cc][2] + bv[cc][2], 0.f);
                v[3] = fmaxf(acc[rt][cc][3] + bv[cc][3], 0.f);
                *(f32x4*)&out[(size_t)row * NCOL + col] = v;
            }
        }
    }
}

extern "C" void kernel_launch(void* const* d_in, const int* in_sizes, int n_in,
                              void* d_out, int out_size, void* d_ws, size_t ws_size,
                              hipStream_t stream) {
    const float* qpos  = (const float*)d_in[0];
    const float* qdir  = (const float*)d_in[1];
    const float* qabil = (const float*)d_in[2];
    const float* qcarr = (const float*)d_in[3];
    const float* qstat = (const float*)d_in[4];
    const float* apos  = (const float*)d_in[5];
    const float* adir  = (const float*)d_in[6];
    const float* aabil = (const float*)d_in[7];
    const float* acarr = (const float*)d_in[8];
    const float* astat = (const float*)d_in[9];
    const int*   cidx  = (const int*)d_in[10];
    const float* W     = (const float*)d_in[11];
    const float* bvec  = (const float*)d_in[12];
    float* out = (float*)d_out;

    const int B = in_sizes[0] / 2;      // query_position is (B,2)
    const int nblocks = B / TM;         // 1024

    const bool ws_ok = (d_ws != nullptr) && (ws_size >= 32768 * sizeof(short));
    if (ws_ok) {
        swz_w_kernel<<<128, 256, 0, stream>>>(W, (short*)d_ws);
        mga_encoder_kernel<true><<<nblocks, THREADS, 0, stream>>>(
            qpos, qdir, qabil, qcarr, qstat, apos, adir, aabil, acarr, astat,
            cidx, W, bvec, (const short*)d_ws, out);
    } else {
        mga_encoder_kernel<false><<<nblocks, THREADS, 0, stream>>>(
            qpos, qdir, qabil, qcarr, qstat, apos, adir, aabil, acarr, astat,
            cidx, W, bvec, nullptr, out);
    }
}

// Round 4
// 272.346 us; speedup vs baseline: 1.2566x; 1.2566x over previous
//
#include <hip/hip_runtime.h>

// MultiGridAgentEncoder v5 (= v4 with launch_bounds(512,4) — the proven no-spill point):
//  - pre-kernel swizzles W -> bf16 in MFMA-fragment order (d_ws), K remapped to
//    slot-stride-14 layout (9 slots x 14, K=126 -> pad 128)
//  - unified slot-unit ballot gather (u==0 query, u==1..8 agent slots)
//  - column-half-split MFMA (32 cols at a time) keeps VGPR = 64 (verified v3b)
//  - operand-swapped MFMA -> lane holds 4 consecutive output cols -> dwordx4 stores
//  - grid 1024 (1 chunk/block); VGPR=64 + 34KB LDS allow 4 blocks/CU residency

#define TM 128          // rows per block
#define XS_LD 136       // LDS row stride in halves (126 used + 10 pad)
#define THREADS 512     // 8 waves: wave grid 2 (rows) x 4 (col-groups of 64)
#define NCOL 256

typedef short short8 __attribute__((ext_vector_type(8)));
typedef float f32x4 __attribute__((ext_vector_type(4)));

__device__ __forceinline__ short f2bf(float x) {
    unsigned u = __builtin_bit_cast(unsigned, x);
    unsigned r = (u + 0x7fffu + ((u >> 16) & 1u)) >> 16;
    return (short)r;
}
__device__ __forceinline__ unsigned pk2(float a, float b) {
    return (unsigned)(unsigned short)f2bf(a) | ((unsigned)(unsigned short)f2bf(b) << 16);
}

// ---- pre-kernel: W (117x256 f32) -> Wb bf16 fragment-order, slot-stride-14 K ----
__global__ __launch_bounds__(256)
void swz_w_kernel(const float* __restrict__ W, short* __restrict__ Wb) {
    const int idx  = blockIdx.x * 256 + threadIdx.x;   // 0..32767
    const int j    = idx & 7;
    const int lane = (idx >> 3) & 63;
    const int ct   = (idx >> 9) & 3;
    const int kt   = (idx >> 11) & 3;
    const int cg   = (idx >> 13) & 3;
    const int kk   = kt * 32 + (lane >> 4) * 8 + j;
    const int u    = kk / 14;
    const int f    = kk - u * 14;
    const int col  = cg * 64 + ct * 16 + (lane & 15);
    float v = 0.f;
    if (u < 9 && f < 13) v = W[(u * 13 + f) * NCOL + col];
    Wb[idx] = f2bf(v);
}

template<bool WS>
__global__ __launch_bounds__(THREADS, 4)
void mga_encoder_kernel(const float* __restrict__ qpos, const float* __restrict__ qdir,
                        const float* __restrict__ qabil, const float* __restrict__ qcarr,
                        const float* __restrict__ qstat,
                        const float* __restrict__ apos, const float* __restrict__ adir,
                        const float* __restrict__ aabil, const float* __restrict__ acarr,
                        const float* __restrict__ astat,
                        const int* __restrict__ cidx,
                        const float* __restrict__ W, const float* __restrict__ bvec,
                        const short* __restrict__ Wb,
                        float* __restrict__ out) {
    __shared__ __align__(16) short Xs[TM * XS_LD];

    const int tid  = threadIdx.x;
    const int wave = tid >> 6;
    const int lane = tid & 63;
    const int ln   = lane & 15;
    const int q    = lane >> 4;
    const int r0w  = (wave & 1) * 64;
    const int cg   = wave >> 1;
    const int c0   = cg * 64;
    const int rowbase = blockIdx.x * TM;

    // zero the K-pad region (halves [126,136) of each row)
    #pragma unroll
    for (int i = tid; i < TM * 5; i += THREADS) {
        const int row = i / 5, w = i - row * 5;
        *(unsigned*)&Xs[row * XS_LD + 126 + w * 2] = 0u;
    }

    const int rr  = tid >> 4;   // row-within-pass (0..31)
    const int u   = tid & 15;   // slot unit: 0 = query, 1..8 = agent slots
    const int grp = tid & 48;   // start lane of 16-lane row group

    // ---- gather: 4 passes of 32 rows; each 16-lane group handles one row ----
    int cs[4];
    #pragma unroll
    for (int p = 0; p < 4; p++)
        cs[p] = cidx[((size_t)(rowbase + p * 32 + rr)) * 16 + u];

    #pragma unroll
    for (int p = 0; p < 4; p++) {
        const int r = p * 32 + rr;
        const size_t b = (size_t)(rowbase + r);
        const int c = cs[p];
        const unsigned long long bg = __ballot(c == 5);  // grey
        const unsigned long long by = __ballot(c == 4);  // yellow
        if (u <= 8) {
            float f0=0.f,f1=0.f,f2=0.f,f3=0.f,f4=0.f,f5=0.f,f6=0.f,
                  f7=0.f,f8=0.f,f9=0.f,f10=0.f,f11=0.f,f12=0.f;
            if (u == 0) {
                const float2 qp = ((const float2*)qpos)[b];
                const float4 qd = ((const float4*)qdir)[b];
                const float2 qa = ((const float2*)qabil)[b];
                const float2 qc = ((const float2*)qcarr)[b];
                f0 = qp.x; f1 = qp.y;
                f2 = qd.x; f3 = qd.y; f4 = qd.z; f5 = qd.w;
                f6 = qa.x; f7 = qa.y;
                f8 = qc.x; f9 = qc.y;
                f10 = qstat[b * 3 + 0]; f11 = qstat[b * 3 + 1]; f12 = qstat[b * 3 + 2];
            } else {
                unsigned mm = (unsigned)(((u <= 4) ? bg : by) >> grp) & 0xFFFFu;
                const int rank = (u - 1) & 3;
                mm = (rank > 0) ? (mm & (mm - 1)) : mm;
                mm = (rank > 1) ? (mm & (mm - 1)) : mm;
                mm = (rank > 2) ? (mm & (mm - 1)) : mm;
                const int j = mm ? (__ffs(mm) - 1) : -1;
                if (j >= 0) {
                    const size_t a = b * 16 + (size_t)j;
                    const float2 pp = ((const float2*)apos)[a];
                    const float4 dd = ((const float4*)adir)[a];
                    const float2 ab = ((const float2*)aabil)[a];
                    const float2 ca = ((const float2*)acarr)[a];
                    f0 = pp.x; f1 = pp.y;
                    f2 = dd.x; f3 = dd.y; f4 = dd.z; f5 = dd.w;
                    f6 = ab.x; f7 = ab.y; f8 = ca.x; f9 = ca.y;
                    f10 = astat[a * 3 + 0]; f11 = astat[a * 3 + 1]; f12 = astat[a * 3 + 2];
                }
            }
            unsigned* xd = (unsigned*)&Xs[r * XS_LD + 14 * u];
            xd[0] = pk2(f0, f1);   xd[1] = pk2(f2, f3);
            xd[2] = pk2(f4, f5);   xd[3] = pk2(f6, f7);
            xd[4] = pk2(f8, f9);   xd[5] = pk2(f10, f11);
            xd[6] = pk2(f12, 0.f);
        }
    }
    __syncthreads();

    // ---- MFMA in two column halves (32 cols each) to keep regs <= 64 ----
    const short8* Wf = (const short8*)Wb;
    #pragma unroll 1
    for (int h = 0; h < 2; h++) {
        short8 bfr[4][2];
        if constexpr (WS) {
            #pragma unroll
            for (int kt = 0; kt < 4; kt++)
                #pragma unroll
                for (int cc = 0; cc < 2; cc++)
                    bfr[kt][cc] = Wf[((cg * 4 + kt) * 4 + 2 * h + cc) * 64 + lane];
        } else {
            #pragma unroll
            for (int kt = 0; kt < 4; kt++)
                #pragma unroll
                for (int cc = 0; cc < 2; cc++) {
                    short8 fr;
                    #pragma unroll
                    for (int j = 0; j < 8; j++) {
                        const int kk = kt * 32 + q * 8 + j;
                        const int uu = kk / 14;
                        const int ff = kk - uu * 14;
                        float v = 0.f;
                        if (uu < 9 && ff < 13)
                            v = W[(uu * 13 + ff) * NCOL + c0 + (2 * h + cc) * 16 + ln];
                        fr[j] = f2bf(v);
                    }
                    bfr[kt][cc] = fr;
                }
        }
        f32x4 bv[2];
        #pragma unroll
        for (int cc = 0; cc < 2; cc++)
            bv[cc] = *(const f32x4*)&bvec[c0 + (2 * h + cc) * 16 + q * 4];

        f32x4 acc[4][2];
        #pragma unroll
        for (int rt = 0; rt < 4; rt++)
            #pragma unroll
            for (int cc = 0; cc < 2; cc++) acc[rt][cc] = (f32x4){0.f, 0.f, 0.f, 0.f};

        #pragma unroll
        for (int kt = 0; kt < 4; kt++) {
            short8 av[4];
            #pragma unroll
            for (int rt = 0; rt < 4; rt++)
                av[rt] = *(const short8*)&Xs[(r0w + rt * 16 + ln) * XS_LD + kt * 32 + q * 8];
            #pragma unroll
            for (int rt = 0; rt < 4; rt++)
                #pragma unroll
                for (int cc = 0; cc < 2; cc++)
                    // swapped operands: lane holds 4 consecutive OUTPUT COLUMNS
                    acc[rt][cc] = __builtin_amdgcn_mfma_f32_16x16x32_bf16(
                        bfr[kt][cc], av[rt], acc[rt][cc], 0, 0, 0);
        }

        #pragma unroll
        for (int rt = 0; rt < 4; rt++) {
            const int row = rowbase + r0w + rt * 16 + ln;
            #pragma unroll
            for (int cc = 0; cc < 2; cc++) {
                const int col = c0 + (2 * h + cc) * 16 + q * 4;
                f32x4 v;
                v[0] = fmaxf(acc[rt][cc][0] + bv[cc][0], 0.f);
                v[1] = fmaxf(acc[rt][cc][1] + bv[cc][1], 0.f);
                v[2] = fmaxf(acc[rt][cc][2] + bv[cc][2], 0.f);
                v[3] = fmaxf(acc[rt][cc][3] + bv[cc][3], 0.f);
                *(f32x4*)&out[(size_t)row * NCOL + col] = v;
            }
        }
    }
}

extern "C" void kernel_launch(void* const* d_in, const int* in_sizes, int n_in,
                              void* d_out, int out_size, void* d_ws, size_t ws_size,
                              hipStream_t stream) {
    const float* qpos  = (const float*)d_in[0];
    const float* qdir  = (const float*)d_in[1];
    const float* qabil = (const float*)d_in[2];
    const float* qcarr = (const float*)d_in[3];
    const float* qstat = (const float*)d_in[4];
    const float* apos  = (const float*)d_in[5];
    const float* adir  = (const float*)d_in[6];
    const float* aabil = (const float*)d_in[7];
    const float* acarr = (const float*)d_in[8];
    const float* astat = (const float*)d_in[9];
    const int*   cidx  = (const int*)d_in[10];
    const float* W     = (const float*)d_in[11];
    const float* bvec  = (const float*)d_in[12];
    float* out = (float*)d_out;

    const int B = in_sizes[0] / 2;      // query_position is (B,2)
    const int nblocks = B / TM;         // 1024

    const bool ws_ok = (d_ws != nullptr) && (ws_size >= 32768 * sizeof(short));
    if (ws_ok) {
        swz_w_kernel<<<128, 256, 0, stream>>>(W, (short*)d_ws);
        mga_encoder_kernel<true><<<nblocks, THREADS, 0, stream>>>(
            qpos, qdir, qabil, qcarr, qstat, apos, adir, aabil, acarr, astat,
            cidx, W, bvec, (const short*)d_ws, out);
    } else {
        mga_encoder_kernel<false><<<nblocks, THREADS, 0, stream>>>(
            qpos, qdir, qabil, qcarr, qstat, apos, adir, aabil, acarr, astat,
            cidx, W, bvec, nullptr, out);
    }
}

// Round 5
// 270.296 us; speedup vs baseline: 1.2662x; 1.0076x over previous
//
#include <hip/hip_runtime.h>

// MultiGridAgentEncoder v6:
//  - COALESCED gather: lane u loads agent u's features unconditionally (contiguous
//    across the 16-lane row group, independent of cidx), packs to 7 bf16-pair dwords,
//    then slot lanes pull their selected agent via __shfl and write LDS (zeros if empty).
//    Removes the cidx->ballot->scattered-load dependent chain and address divergence.
//  - pre-kernel swizzles W -> bf16 fragment order (d_ws), slot-stride-14 K (9x14=126)
//  - column-half-split MFMA keeps VGPR low; swapped operands -> dwordx4 stores
//  - grid 1024, __launch_bounds__(512,4) (proven no-spill point)

#define TM 128          // rows per block
#define XS_LD 136       // LDS row stride in halves (126 used + 10 pad)
#define THREADS 512     // 8 waves: wave grid 2 (rows) x 4 (col-groups of 64)
#define NCOL 256

typedef short short8 __attribute__((ext_vector_type(8)));
typedef float f32x4 __attribute__((ext_vector_type(4)));

__device__ __forceinline__ short f2bf(float x) {
    unsigned u = __builtin_bit_cast(unsigned, x);
    unsigned r = (u + 0x7fffu + ((u >> 16) & 1u)) >> 16;
    return (short)r;
}
__device__ __forceinline__ unsigned pk2(float a, float b) {
    return (unsigned)(unsigned short)f2bf(a) | ((unsigned)(unsigned short)f2bf(b) << 16);
}

// ---- pre-kernel: W (117x256 f32) -> Wb bf16 fragment-order, slot-stride-14 K ----
__global__ __launch_bounds__(256)
void swz_w_kernel(const float* __restrict__ W, short* __restrict__ Wb) {
    const int idx  = blockIdx.x * 256 + threadIdx.x;   // 0..32767
    const int j    = idx & 7;
    const int lane = (idx >> 3) & 63;
    const int ct   = (idx >> 9) & 3;
    const int kt   = (idx >> 11) & 3;
    const int cg   = (idx >> 13) & 3;
    const int kk   = kt * 32 + (lane >> 4) * 8 + j;
    const int u    = kk / 14;
    const int f    = kk - u * 14;
    const int col  = cg * 64 + ct * 16 + (lane & 15);
    float v = 0.f;
    if (u < 9 && f < 13) v = W[(u * 13 + f) * NCOL + col];
    Wb[idx] = f2bf(v);
}

template<bool WS>
__global__ __launch_bounds__(THREADS, 4)
void mga_encoder_kernel(const float* __restrict__ qpos, const float* __restrict__ qdir,
                        const float* __restrict__ qabil, const float* __restrict__ qcarr,
                        const float* __restrict__ qstat,
                        const float* __restrict__ apos, const float* __restrict__ adir,
                        const float* __restrict__ aabil, const float* __restrict__ acarr,
                        const float* __restrict__ astat,
                        const int* __restrict__ cidx,
                        const float* __restrict__ W, const float* __restrict__ bvec,
                        const short* __restrict__ Wb,
                        float* __restrict__ out) {
    __shared__ __align__(16) short Xs[TM * XS_LD];

    const int tid  = threadIdx.x;
    const int wave = tid >> 6;
    const int lane = tid & 63;
    const int ln   = lane & 15;
    const int q    = lane >> 4;
    const int r0w  = (wave & 1) * 64;
    const int cg   = wave >> 1;
    const int c0   = cg * 64;
    const int rowbase = blockIdx.x * TM;

    // zero the K-pad region (halves [126,136) of each row)
    #pragma unroll
    for (int i = tid; i < TM * 5; i += THREADS) {
        const int row = i / 5, w = i - row * 5;
        *(unsigned*)&Xs[row * XS_LD + 126 + w * 2] = 0u;
    }

    const int rr  = tid >> 4;   // row-within-pass (0..31)
    const int u   = tid & 15;   // lane's agent index AND slot unit
    const int grp = lane & 48;  // start lane (within wave) of my 16-lane row group

    // ---- query features: 2 waves, coalesced ----
    if (tid < TM) {
        const size_t b = (size_t)(rowbase + tid);
        const float2 qp = ((const float2*)qpos)[b];
        const float4 qd = ((const float4*)qdir)[b];
        const float2 qa = ((const float2*)qabil)[b];
        const float2 qc = ((const float2*)qcarr)[b];
        const float s0 = qstat[b * 3 + 0];
        const float s1 = qstat[b * 3 + 1];
        const float s2 = qstat[b * 3 + 2];
        unsigned* xd = (unsigned*)&Xs[tid * XS_LD];
        xd[0] = pk2(qp.x, qp.y); xd[1] = pk2(qd.x, qd.y);
        xd[2] = pk2(qd.z, qd.w); xd[3] = pk2(qa.x, qa.y);
        xd[4] = pk2(qc.x, qc.y); xd[5] = pk2(s0, s1);
        xd[6] = pk2(s2, 0.f);
    }

    // ---- agent gather: 4 passes of 32 rows; 16-lane group per row ----
    int cs[4];
    #pragma unroll
    for (int p = 0; p < 4; p++)
        cs[p] = cidx[((size_t)(rowbase + p * 32 + rr)) * 16 + u];

    #pragma unroll
    for (int p = 0; p < 4; p++) {
        const int r = p * 32 + rr;
        const size_t b = (size_t)(rowbase + r);
        const size_t a = b * 16 + (size_t)u;

        // unconditional coalesced loads: lane u owns agent u
        const float2 pp = ((const float2*)apos)[a];
        const float4 dd = ((const float4*)adir)[a];
        const float2 ab = ((const float2*)aabil)[a];
        const float2 ca = ((const float2*)acarr)[a];
        const float s0 = astat[a * 3 + 0];
        const float s1 = astat[a * 3 + 1];
        const float s2 = astat[a * 3 + 2];
        unsigned d0 = pk2(pp.x, pp.y), d1 = pk2(dd.x, dd.y);
        unsigned d2 = pk2(dd.z, dd.w), d3 = pk2(ab.x, ab.y);
        unsigned d4 = pk2(ca.x, ca.y), d5 = pk2(s0, s1);
        unsigned d6 = pk2(s2, 0.f);

        // ballot over own agent's color
        const int c = cs[p];
        const unsigned long long bg = __ballot(c == 5);  // grey
        const unsigned long long by = __ballot(c == 4);  // yellow

        // slot lane u (1..8) selects its source agent j via rank-th set bit
        int j = -1;
        if (u >= 1 && u <= 8) {
            unsigned mm = (unsigned)(((u <= 4) ? bg : by) >> grp) & 0xFFFFu;
            const int rank = (u - 1) & 3;
            mm = (rank > 0) ? (mm & (mm - 1)) : mm;
            mm = (rank > 1) ? (mm & (mm - 1)) : mm;
            mm = (rank > 2) ? (mm & (mm - 1)) : mm;
            j = mm ? (__ffs(mm) - 1) : -1;
        }
        const int src = grp + (j >= 0 ? j : u);   // valid lane for everyone

        // route agent j's packed dwords to the slot lane (all lanes shuffle)
        unsigned e0 = (unsigned)__shfl((int)d0, src, 64);
        unsigned e1 = (unsigned)__shfl((int)d1, src, 64);
        unsigned e2 = (unsigned)__shfl((int)d2, src, 64);
        unsigned e3 = (unsigned)__shfl((int)d3, src, 64);
        unsigned e4 = (unsigned)__shfl((int)d4, src, 64);
        unsigned e5 = (unsigned)__shfl((int)d5, src, 64);
        unsigned e6 = (unsigned)__shfl((int)d6, src, 64);

        if (u >= 1 && u <= 8) {
            const bool ok = (j >= 0);
            unsigned* xd = (unsigned*)&Xs[r * XS_LD + 14 * u];
            xd[0] = ok ? e0 : 0u;  xd[1] = ok ? e1 : 0u;
            xd[2] = ok ? e2 : 0u;  xd[3] = ok ? e3 : 0u;
            xd[4] = ok ? e4 : 0u;  xd[5] = ok ? e5 : 0u;
            xd[6] = ok ? e6 : 0u;
        }
    }
    __syncthreads();

    // ---- MFMA in two column halves (32 cols each) to keep regs <= 64 ----
    const short8* Wf = (const short8*)Wb;
    #pragma unroll 1
    for (int h = 0; h < 2; h++) {
        short8 bfr[4][2];
        if constexpr (WS) {
            #pragma unroll
            for (int kt = 0; kt < 4; kt++)
                #pragma unroll
                for (int cc = 0; cc < 2; cc++)
                    bfr[kt][cc] = Wf[((cg * 4 + kt) * 4 + 2 * h + cc) * 64 + lane];
        } else {
            #pragma unroll
            for (int kt = 0; kt < 4; kt++)
                #pragma unroll
                for (int cc = 0; cc < 2; cc++) {
                    short8 fr;
                    #pragma unroll
                    for (int jj = 0; jj < 8; jj++) {
                        const int kk = kt * 32 + q * 8 + jj;
                        const int uu = kk / 14;
                        const int ff = kk - uu * 14;
                        float v = 0.f;
                        if (uu < 9 && ff < 13)
                            v = W[(uu * 13 + ff) * NCOL + c0 + (2 * h + cc) * 16 + ln];
                        fr[jj] = f2bf(v);
                    }
                    bfr[kt][cc] = fr;
                }
        }
        f32x4 bv[2];
        #pragma unroll
        for (int cc = 0; cc < 2; cc++)
            bv[cc] = *(const f32x4*)&bvec[c0 + (2 * h + cc) * 16 + q * 4];

        f32x4 acc[4][2];
        #pragma unroll
        for (int rt = 0; rt < 4; rt++)
            #pragma unroll
            for (int cc = 0; cc < 2; cc++) acc[rt][cc] = (f32x4){0.f, 0.f, 0.f, 0.f};

        #pragma unroll
        for (int kt = 0; kt < 4; kt++) {
            short8 av[4];
            #pragma unroll
            for (int rt = 0; rt < 4; rt++)
                av[rt] = *(const short8*)&Xs[(r0w + rt * 16 + ln) * XS_LD + kt * 32 + q * 8];
            #pragma unroll
            for (int rt = 0; rt < 4; rt++)
                #pragma unroll
                for (int cc = 0; cc < 2; cc++)
                    // swapped operands: lane holds 4 consecutive OUTPUT COLUMNS
                    acc[rt][cc] = __builtin_amdgcn_mfma_f32_16x16x32_bf16(
                        bfr[kt][cc], av[rt], acc[rt][cc], 0, 0, 0);
        }

        #pragma unroll
        for (int rt = 0; rt < 4; rt++) {
            const int row = rowbase + r0w + rt * 16 + ln;
            #pragma unroll
            for (int cc = 0; cc < 2; cc++) {
                const int col = c0 + (2 * h + cc) * 16 + q * 4;
                f32x4 v;
                v[0] = fmaxf(acc[rt][cc][0] + bv[cc][0], 0.f);
                v[1] = fmaxf(acc[rt][cc][1] + bv[cc][1], 0.f);
                v[2] = fmaxf(acc[rt][cc][2] + bv[cc][2], 0.f);
                v[3] = fmaxf(acc[rt][cc][3] + bv[cc][3], 0.f);
                *(f32x4*)&out[(size_t)row * NCOL + col] = v;
            }
        }
    }
}

extern "C" void kernel_launch(void* const* d_in, const int* in_sizes, int n_in,
                              void* d_out, int out_size, void* d_ws, size_t ws_size,
                              hipStream_t stream) {
    const float* qpos  = (const float*)d_in[0];
    const float* qdir  = (const float*)d_in[1];
    const float* qabil = (const float*)d_in[2];
    const float* qcarr = (const float*)d_in[3];
    const float* qstat = (const float*)d_in[4];
    const float* apos  = (const float*)d_in[5];
    const float* adir  = (const float*)d_in[6];
    const float* aabil = (const float*)d_in[7];
    const float* acarr = (const float*)d_in[8];
    const float* astat = (const float*)d_in[9];
    const int*   cidx  = (const int*)d_in[10];
    const float* W     = (const float*)d_in[11];
    const float* bvec  = (const float*)d_in[12];
    float* out = (float*)d_out;

    const int B = in_sizes[0] / 2;      // query_position is (B,2)
    const int nblocks = B / TM;         // 1024

    const bool ws_ok = (d_ws != nullptr) && (ws_size >= 32768 * sizeof(short));
    if (ws_ok) {
        swz_w_kernel<<<128, 256, 0, stream>>>(W, (short*)d_ws);
        mga_encoder_kernel<true><<<nblocks, THREADS, 0, stream>>>(
            qpos, qdir, qabil, qcarr, qstat, apos, adir, aabil, acarr, astat,
            cidx, W, bvec, (const short*)d_ws, out);
    } else {
        mga_encoder_kernel<false><<<nblocks, THREADS, 0, stream>>>(
            qpos, qdir, qabil, qcarr, qstat, apos, adir, aabil, acarr, astat,
            cidx, W, bvec, nullptr, out);
    }
}

// Round 7
// 266.235 us; speedup vs baseline: 1.2855x; 1.0153x over previous
//
#include <hip/hip_runtime.h>

// MultiGridAgentEncoder v7b: software-pipelined persistent blocks (resubmit of v7;
// round-6 failure was infra, source audited hang-free).
//  - grid 256 (1 block/CU), 4 chunks of TM=128 rows per block
//  - 2-deep pipeline: issue chunk t+1 global loads (into registers) BEFORE
//    packing/computing chunk t -> read stream stays live through compute+store
//  - double-buffered LDS X (2 x 128 x 136 halves = 68KB); one barrier per chunk
//  - gather: lane u loads agent u coalesced; slot lanes pull via __shfl (v6 logic)
//  - pre-kernel W->bf16 fragment order in d_ws; slot-stride-14 K (9x14=126, pad 128)
//  - column-half-split MFMA, swapped operands -> dwordx4 stores (plain, cached)

#define TM 128          // rows per chunk
#define XS_LD 136       // LDS row stride in halves (126 used + 10 pad)
#define THREADS 512     // 8 waves: wave grid 2 (rows) x 4 (col-groups of 64)
#define NCOL 256
#define GRID 256

typedef short short8 __attribute__((ext_vector_type(8)));
typedef float f32x4 __attribute__((ext_vector_type(4)));

struct Raw { float v[13]; };   // accessed only with compile-time indices (unrolled)

__device__ __forceinline__ short f2bf(float x) {
    unsigned u = __builtin_bit_cast(unsigned, x);
    unsigned r = (u + 0x7fffu + ((u >> 16) & 1u)) >> 16;
    return (short)r;
}
__device__ __forceinline__ unsigned pk2(float a, float b) {
    return (unsigned)(unsigned short)f2bf(a) | ((unsigned)(unsigned short)f2bf(b) << 16);
}

__device__ __forceinline__ void load_agent(const float* __restrict__ apos,
                                           const float* __restrict__ adir,
                                           const float* __restrict__ aabil,
                                           const float* __restrict__ acarr,
                                           const float* __restrict__ astat,
                                           size_t a, Raw& r) {
    const float2 pp = ((const float2*)apos)[a];
    const float4 dd = ((const float4*)adir)[a];
    const float2 ab = ((const float2*)aabil)[a];
    const float2 ca = ((const float2*)acarr)[a];
    r.v[0] = pp.x;  r.v[1] = pp.y;
    r.v[2] = dd.x;  r.v[3] = dd.y;  r.v[4] = dd.z;  r.v[5] = dd.w;
    r.v[6] = ab.x;  r.v[7] = ab.y;  r.v[8] = ca.x;  r.v[9] = ca.y;
    r.v[10] = astat[a * 3 + 0]; r.v[11] = astat[a * 3 + 1]; r.v[12] = astat[a * 3 + 2];
}

__device__ __forceinline__ void load_query(const float* __restrict__ qpos,
                                           const float* __restrict__ qdir,
                                           const float* __restrict__ qabil,
                                           const float* __restrict__ qcarr,
                                           const float* __restrict__ qstat,
                                           size_t b, Raw& r) {
    const float2 qp = ((const float2*)qpos)[b];
    const float4 qd = ((const float4*)qdir)[b];
    const float2 qa = ((const float2*)qabil)[b];
    const float2 qc = ((const float2*)qcarr)[b];
    r.v[0] = qp.x;  r.v[1] = qp.y;
    r.v[2] = qd.x;  r.v[3] = qd.y;  r.v[4] = qd.z;  r.v[5] = qd.w;
    r.v[6] = qa.x;  r.v[7] = qa.y;  r.v[8] = qc.x;  r.v[9] = qc.y;
    r.v[10] = qstat[b * 3 + 0]; r.v[11] = qstat[b * 3 + 1]; r.v[12] = qstat[b * 3 + 2];
}

// ---- pre-kernel: W (117x256 f32) -> Wb bf16 fragment-order, slot-stride-14 K ----
__global__ __launch_bounds__(256)
void swz_w_kernel(const float* __restrict__ W, short* __restrict__ Wb) {
    const int idx  = blockIdx.x * 256 + threadIdx.x;   // 0..32767
    const int j    = idx & 7;
    const int lane = (idx >> 3) & 63;
    const int ct   = (idx >> 9) & 3;
    const int kt   = (idx >> 11) & 3;
    const int cg   = (idx >> 13) & 3;
    const int kk   = kt * 32 + (lane >> 4) * 8 + j;
    const int u    = kk / 14;
    const int f    = kk - u * 14;
    const int col  = cg * 64 + ct * 16 + (lane & 15);
    float v = 0.f;
    if (u < 9 && f < 13) v = W[(u * 13 + f) * NCOL + col];
    Wb[idx] = f2bf(v);
}

template<bool WS>
__global__ __launch_bounds__(THREADS, 2)
void mga_encoder_kernel(const float* __restrict__ qpos, const float* __restrict__ qdir,
                        const float* __restrict__ qabil, const float* __restrict__ qcarr,
                        const float* __restrict__ qstat,
                        const float* __restrict__ apos, const float* __restrict__ adir,
                        const float* __restrict__ aabil, const float* __restrict__ acarr,
                        const float* __restrict__ astat,
                        const int* __restrict__ cidx,
                        const float* __restrict__ W, const float* __restrict__ bvec,
                        const short* __restrict__ Wb,
                        float* __restrict__ out, int nchunks) {
    __shared__ __align__(16) short Xs[2][TM * XS_LD];

    const int tid  = threadIdx.x;
    const int wave = tid >> 6;
    const int lane = tid & 63;
    const int ln   = lane & 15;
    const int q    = lane >> 4;
    const int r0w  = (wave & 1) * 64;
    const int cg   = wave >> 1;
    const int c0   = cg * 64;

    // zero the K-pad region (halves [126,136)) of both buffers, once
    #pragma unroll
    for (int bz = 0; bz < 2; bz++)
        for (int i = tid; i < TM * 5; i += THREADS) {
            const int row = i / 5, w = i - row * 5;
            *(unsigned*)&Xs[bz][row * XS_LD + 126 + w * 2] = 0u;
        }

    const int rr  = tid >> 4;   // row-within-pass (0..31)
    const int u   = tid & 15;   // lane's agent index AND slot unit
    const int grp = lane & 48;  // start lane (within wave) of my 16-lane row group
    const int grid = gridDim.x;

    int tcur = blockIdx.x;
    if (tcur >= nchunks) return;   // no barriers crossed yet: safe

    // ---- prologue: issue loads for chunk tcur ----
    Raw ar[4]; int cs[4]; Raw qr;
    {
        const int rowbase = tcur * TM;
        #pragma unroll
        for (int p = 0; p < 4; p++)
            cs[p] = cidx[((size_t)(rowbase + p * 32 + rr)) * 16 + u];
        #pragma unroll
        for (int p = 0; p < 4; p++)
            load_agent(apos, adir, aabil, acarr, astat,
                       ((size_t)(rowbase + p * 32 + rr)) * 16 + (size_t)u, ar[p]);
        if (tid < TM) load_query(qpos, qdir, qabil, qcarr, qstat,
                                 (size_t)(rowbase + tid), qr);
    }

    int buf = 0;
    for (;;) {
        const int tnext = tcur + grid;
        const bool more = (tnext < nchunks);   // uniform across block

        // ---- issue next chunk's loads (fire-and-forget into registers) ----
        Raw arn[4]; int csn[4]; Raw qrn;
        if (more) {
            const int rowbase = tnext * TM;
            #pragma unroll
            for (int p = 0; p < 4; p++)
                csn[p] = cidx[((size_t)(rowbase + p * 32 + rr)) * 16 + u];
            #pragma unroll
            for (int p = 0; p < 4; p++)
                load_agent(apos, adir, aabil, acarr, astat,
                           ((size_t)(rowbase + p * 32 + rr)) * 16 + (size_t)u, arn[p]);
            if (tid < TM) load_query(qpos, qdir, qabil, qcarr, qstat,
                                     (size_t)(rowbase + tid), qrn);
        }

        // ---- pack current chunk into Xs[buf] ----
        if (tid < TM) {
            unsigned* xd = (unsigned*)&Xs[buf][tid * XS_LD];
            xd[0] = pk2(qr.v[0], qr.v[1]);   xd[1] = pk2(qr.v[2], qr.v[3]);
            xd[2] = pk2(qr.v[4], qr.v[5]);   xd[3] = pk2(qr.v[6], qr.v[7]);
            xd[4] = pk2(qr.v[8], qr.v[9]);   xd[5] = pk2(qr.v[10], qr.v[11]);
            xd[6] = pk2(qr.v[12], 0.f);
        }
        #pragma unroll
        for (int p = 0; p < 4; p++) {
            const int r = p * 32 + rr;
            const unsigned d0 = pk2(ar[p].v[0], ar[p].v[1]);
            const unsigned d1 = pk2(ar[p].v[2], ar[p].v[3]);
            const unsigned d2 = pk2(ar[p].v[4], ar[p].v[5]);
            const unsigned d3 = pk2(ar[p].v[6], ar[p].v[7]);
            const unsigned d4 = pk2(ar[p].v[8], ar[p].v[9]);
            const unsigned d5 = pk2(ar[p].v[10], ar[p].v[11]);
            const unsigned d6 = pk2(ar[p].v[12], 0.f);

            const int c = cs[p];
            const unsigned long long bg = __ballot(c == 5);  // grey
            const unsigned long long by = __ballot(c == 4);  // yellow

            int j = -1;
            if (u >= 1 && u <= 8) {
                unsigned mm = (unsigned)(((u <= 4) ? bg : by) >> grp) & 0xFFFFu;
                const int rank = (u - 1) & 3;
                mm = (rank > 0) ? (mm & (mm - 1)) : mm;
                mm = (rank > 1) ? (mm & (mm - 1)) : mm;
                mm = (rank > 2) ? (mm & (mm - 1)) : mm;
                j = mm ? (__ffs(mm) - 1) : -1;
            }
            const int src = grp + (j >= 0 ? j : u);

            const unsigned e0 = (unsigned)__shfl((int)d0, src, 64);
            const unsigned e1 = (unsigned)__shfl((int)d1, src, 64);
            const unsigned e2 = (unsigned)__shfl((int)d2, src, 64);
            const unsigned e3 = (unsigned)__shfl((int)d3, src, 64);
            const unsigned e4 = (unsigned)__shfl((int)d4, src, 64);
            const unsigned e5 = (unsigned)__shfl((int)d5, src, 64);
            const unsigned e6 = (unsigned)__shfl((int)d6, src, 64);

            if (u >= 1 && u <= 8) {
                const bool ok = (j >= 0);
                unsigned* xd = (unsigned*)&Xs[buf][r * XS_LD + 14 * u];
                xd[0] = ok ? e0 : 0u;  xd[1] = ok ? e1 : 0u;
                xd[2] = ok ? e2 : 0u;  xd[3] = ok ? e3 : 0u;
                xd[4] = ok ? e4 : 0u;  xd[5] = ok ? e5 : 0u;
                xd[6] = ok ? e6 : 0u;
            }
        }
        __syncthreads();

        // ---- compute chunk tcur from Xs[buf] ----
        const int rowbase = tcur * TM;
        const short8* Wf = (const short8*)Wb;
        #pragma unroll 1
        for (int h = 0; h < 2; h++) {
            short8 bfr[4][2];
            if constexpr (WS) {
                #pragma unroll
                for (int kt = 0; kt < 4; kt++)
                    #pragma unroll
                    for (int cc = 0; cc < 2; cc++)
                        bfr[kt][cc] = Wf[((cg * 4 + kt) * 4 + 2 * h + cc) * 64 + lane];
            } else {
                #pragma unroll
                for (int kt = 0; kt < 4; kt++)
                    #pragma unroll
                    for (int cc = 0; cc < 2; cc++) {
                        short8 fr;
                        #pragma unroll
                        for (int jj = 0; jj < 8; jj++) {
                            const int kk = kt * 32 + q * 8 + jj;
                            const int uu = kk / 14;
                            const int ff = kk - uu * 14;
                            float v = 0.f;
                            if (uu < 9 && ff < 13)
                                v = W[(uu * 13 + ff) * NCOL + c0 + (2 * h + cc) * 16 + ln];
                            fr[jj] = f2bf(v);
                        }
                        bfr[kt][cc] = fr;
                    }
            }
            f32x4 bv[2];
            #pragma unroll
            for (int cc = 0; cc < 2; cc++)
                bv[cc] = *(const f32x4*)&bvec[c0 + (2 * h + cc) * 16 + q * 4];

            f32x4 acc[4][2];
            #pragma unroll
            for (int rt = 0; rt < 4; rt++)
                #pragma unroll
                for (int cc = 0; cc < 2; cc++) acc[rt][cc] = (f32x4){0.f, 0.f, 0.f, 0.f};

            #pragma unroll
            for (int kt = 0; kt < 4; kt++) {
                short8 av[4];
                #pragma unroll
                for (int rt = 0; rt < 4; rt++)
                    av[rt] = *(const short8*)&Xs[buf][(r0w + rt * 16 + ln) * XS_LD + kt * 32 + q * 8];
                #pragma unroll
                for (int rt = 0; rt < 4; rt++)
                    #pragma unroll
                    for (int cc = 0; cc < 2; cc++)
                        // swapped operands: lane holds 4 consecutive OUTPUT COLUMNS
                        acc[rt][cc] = __builtin_amdgcn_mfma_f32_16x16x32_bf16(
                            bfr[kt][cc], av[rt], acc[rt][cc], 0, 0, 0);
            }

            #pragma unroll
            for (int rt = 0; rt < 4; rt++) {
                const int row = rowbase + r0w + rt * 16 + ln;
                #pragma unroll
                for (int cc = 0; cc < 2; cc++) {
                    const int col = c0 + (2 * h + cc) * 16 + q * 4;
                    f32x4 v;
                    v[0] = fmaxf(acc[rt][cc][0] + bv[cc][0], 0.f);
                    v[1] = fmaxf(acc[rt][cc][1] + bv[cc][1], 0.f);
                    v[2] = fmaxf(acc[rt][cc][2] + bv[cc][2], 0.f);
                    v[3] = fmaxf(acc[rt][cc][3] + bv[cc][3], 0.f);
                    *(f32x4*)&out[(size_t)row * NCOL + col] = v;
                }
            }
        }

        if (!more) break;

        // ---- rotate pipeline registers (fully unrolled, static indices) ----
        #pragma unroll
        for (int p = 0; p < 4; p++) {
            cs[p] = csn[p];
            #pragma unroll
            for (int k = 0; k < 13; k++) ar[p].v[k] = arn[p].v[k];
        }
        #pragma unroll
        for (int k = 0; k < 13; k++) qr.v[k] = qrn.v[k];
        tcur = tnext;
        buf ^= 1;
    }
}

extern "C" void kernel_launch(void* const* d_in, const int* in_sizes, int n_in,
                              void* d_out, int out_size, void* d_ws, size_t ws_size,
                              hipStream_t stream) {
    const float* qpos  = (const float*)d_in[0];
    const float* qdir  = (const float*)d_in[1];
    const float* qabil = (const float*)d_in[2];
    const float* qcarr = (const float*)d_in[3];
    const float* qstat = (const float*)d_in[4];
    const float* apos  = (const float*)d_in[5];
    const float* adir  = (const float*)d_in[6];
    const float* aabil = (const float*)d_in[7];
    const float* acarr = (const float*)d_in[8];
    const float* astat = (const float*)d_in[9];
    const int*   cidx  = (const int*)d_in[10];
    const float* W     = (const float*)d_in[11];
    const float* bvec  = (const float*)d_in[12];
    float* out = (float*)d_out;

    const int B = in_sizes[0] / 2;      // query_position is (B,2)
    const int nchunks = B / TM;         // 1024
    const int grid = nchunks < GRID ? nchunks : GRID;

    const bool ws_ok = (d_ws != nullptr) && (ws_size >= 32768 * sizeof(short));
    if (ws_ok) {
        swz_w_kernel<<<128, 256, 0, stream>>>(W, (short*)d_ws);
        mga_encoder_kernel<true><<<grid, THREADS, 0, stream>>>(
            qpos, qdir, qabil, qcarr, qstat, apos, adir, aabil, acarr, astat,
            cidx, W, bvec, (const short*)d_ws, out, nchunks);
    } else {
        mga_encoder_kernel<false><<<grid, THREADS, 0, stream>>>(
            qpos, qdir, qabil, qcarr, qstat, apos, adir, aabil, acarr, astat,
            cidx, W, bvec, nullptr, out, nchunks);
    }
}